// Round 1
// baseline (333.073 us; speedup 1.0000x reference)
//
#include <hip/hip_runtime.h>
#include <cstdint>
#include <cstddef>

typedef unsigned short u16;
typedef unsigned int u32;
using bf16x8 = __attribute__((ext_vector_type(8))) __bf16;
using f32x4  = __attribute__((ext_vector_type(4))) float;

#define N_EMBD 1024
#define N_HEAD 16
#define HEAD_DIM 64
#define BATCH 2
#define SEQ 2048
#define M_TOT (BATCH * SEQ)  // 4096

// ---------- helpers ----------

__device__ __forceinline__ u16 f2bf(float f) {
  union { float f; u32 u; } v;
  v.f = f;
  u32 u = v.u;
  u32 r = (u + 0x7FFFu + ((u >> 16) & 1u)) >> 16;  // RNE
  return (u16)r;
}

// async global->LDS, 16B per lane; dst must be wave-uniform base (HW adds lane*16)
__device__ __forceinline__ void g2l16(const void* g, void* l) {
  __builtin_amdgcn_global_load_lds((__attribute__((address_space(1))) void*)(g),
                                   (__attribute__((address_space(3))) void*)(l),
                                   16, 0, 0);
}

// ---------- fp32 -> bf16 convert (x) ----------

__global__ __launch_bounds__(256) void conv_bf16_kernel(const float* __restrict__ src,
                                                        u16* __restrict__ dst) {
  int i = (blockIdx.x * 256 + threadIdx.x) * 8;
  float4 a = *(const float4*)(src + i);
  float4 b = *(const float4*)(src + i + 4);
  union { u16 s[8]; uint4 v; } o;
  o.s[0] = f2bf(a.x); o.s[1] = f2bf(a.y); o.s[2] = f2bf(a.z); o.s[3] = f2bf(a.w);
  o.s[4] = f2bf(b.x); o.s[5] = f2bf(b.y); o.s[6] = f2bf(b.z); o.s[7] = f2bf(b.w);
  *(uint4*)(dst + i) = o.v;
}

// ---------- fp32 [R][C] -> bf16 [C][R] transpose ----------

__global__ __launch_bounds__(256) void transp_bf16_kernel(const float* __restrict__ src,
                                                          u16* __restrict__ dst, int R, int C) {
  __shared__ float tile[64][65];
  const int c0 = blockIdx.x * 64, r0 = blockIdx.y * 64;
  const int tid = threadIdx.x;
#pragma unroll
  for (int i = 0; i < 16; ++i) {
    int idx = tid + i * 256;
    int r = idx >> 6, c = idx & 63;
    tile[r][c] = src[(size_t)(r0 + r) * C + (c0 + c)];
  }
  __syncthreads();
#pragma unroll
  for (int i = 0; i < 16; ++i) {
    int idx = tid + i * 256;
    int cc = idx >> 6, rr = idx & 63;
    dst[(size_t)(c0 + cc) * R + (r0 + rr)] = f2bf(tile[rr][cc]);
  }
}

// ---------- GEMM: C[M,N] = A[M,K] * Bt[N,K]^T + bias ----------
// MODE 0: fp32 out row-major [M,N]
// MODE 1: qkv epilogue -> q[B,H,S,D], k[B,H,S,D], v^T[B,H,D,S], all bf16

template <int MODE>
__global__ __launch_bounds__(256) void gemm_bt(const u16* __restrict__ A,
                                               const u16* __restrict__ Bt,
                                               const float* __restrict__ bias,
                                               float* __restrict__ outF,
                                               u16* __restrict__ qb, u16* __restrict__ kb,
                                               u16* __restrict__ vtb, int M, int N, int K) {
  __shared__ u16 As[128 * 32];
  __shared__ u16 Bs[128 * 32];
  const int tid = threadIdx.x;
  const int wid = tid >> 6;
  const int lane = tid & 63;
  const int quad = lane >> 4;
  const int l15 = lane & 15;
  const int m0 = blockIdx.y * 128;
  const int n0 = blockIdx.x * 128;
  const int wm = wid >> 1, wn = wid & 1;

  f32x4 acc[4][4];
#pragma unroll
  for (int i = 0; i < 4; ++i)
#pragma unroll
    for (int j = 0; j < 4; ++j) acc[i][j] = (f32x4){0.f, 0.f, 0.f, 0.f};

  const int lrow = lane >> 2;          // 0..15
  const int lchunk = (lane & 3) * 8;   // element offset within 32-col row

  for (int k0 = 0; k0 < K; k0 += 32) {
#pragma unroll
    for (int i = 0; i < 2; ++i) {
      int li = wid * 2 + i;
      int r = li * 16 + lrow;
      g2l16(A + (size_t)(m0 + r) * K + k0 + lchunk, &As[li * 512]);
      g2l16(Bt + (size_t)(n0 + r) * K + k0 + lchunk, &Bs[li * 512]);
    }
    __syncthreads();
    bf16x8 af[4], bfv[4];
#pragma unroll
    for (int i = 0; i < 4; ++i)
      af[i] = *(const bf16x8*)&As[(wm * 64 + i * 16 + l15) * 32 + quad * 8];
#pragma unroll
    for (int j = 0; j < 4; ++j)
      bfv[j] = *(const bf16x8*)&Bs[(wn * 64 + j * 16 + l15) * 32 + quad * 8];
#pragma unroll
    for (int i = 0; i < 4; ++i)
#pragma unroll
      for (int j = 0; j < 4; ++j)
        acc[i][j] = __builtin_amdgcn_mfma_f32_16x16x32_bf16(af[i], bfv[j], acc[i][j], 0, 0, 0);
    __syncthreads();
  }

  float bj[4];
#pragma unroll
  for (int j = 0; j < 4; ++j) bj[j] = bias[n0 + wn * 64 + j * 16 + l15];

#pragma unroll
  for (int i = 0; i < 4; ++i) {
#pragma unroll
    for (int j = 0; j < 4; ++j) {
      int col = n0 + wn * 64 + j * 16 + l15;
#pragma unroll
      for (int r = 0; r < 4; ++r) {
        int m_g = m0 + wm * 64 + i * 16 + quad * 4 + r;
        float v = acc[i][j][r] + bj[j];
        if (MODE == 0) {
          outF[(size_t)m_g * N + col] = v;
        } else {
          int which = col >> 10;      // 0=q 1=k 2=v (uniform per block: n0 is 128-aligned)
          int e = col & 1023;
          int h = e >> 6, d = e & 63;
          int b = m_g >> 11, s = m_g & 2047;
          int bh = b * N_HEAD + h;
          u16 bv = f2bf(v);
          if (which == 0)
            qb[((size_t)bh * SEQ + s) * HEAD_DIM + d] = bv;
          else if (which == 1)
            kb[((size_t)bh * SEQ + s) * HEAD_DIM + d] = bv;
          else
            vtb[((size_t)bh * HEAD_DIM + d) * SEQ + s] = bv;
        }
      }
    }
  }
}

// ---------- flash attention (causal), 64-row Q tile, 4 waves x 16 rows ----------

__global__ __launch_bounds__(256) void attn_kernel(const u16* __restrict__ q,
                                                   const u16* __restrict__ k,
                                                   const u16* __restrict__ vt,
                                                   u16* __restrict__ ctx) {
  __shared__ u16 Qs[64 * 64];
  __shared__ u16 Ks[64 * 64];
  __shared__ u16 Vs[64 * 64];       // [d][key]
  __shared__ u16 Ps[4 * 16 * 64];   // per-wave P staging (C-layout -> A-layout)
  const int tid = threadIdx.x;
  const int wid = tid >> 6;
  const int lane = tid & 63;
  const int quad = lane >> 4;
  const int l15 = lane & 15;
  const int qt = blockIdx.x;   // q tile (64 rows)
  const int bh = blockIdx.y;   // b*16+h
  const size_t base = (size_t)bh * SEQ * HEAD_DIM;

  const int lrow8 = lane >> 3;       // 0..7
  const int lch8 = (lane & 7) * 8;

  // stage Q tile (rows qt*64 .. +63); drained by first in-loop barrier
#pragma unroll
  for (int i = 0; i < 2; ++i) {
    int li = wid * 2 + i;
    g2l16(q + base + (size_t)(qt * 64 + li * 8 + lrow8) * HEAD_DIM + lch8, &Qs[li * 512]);
  }

  float m_i[4], l_i[4];
  f32x4 o[4];
#pragma unroll
  for (int r = 0; r < 4; ++r) { m_i[r] = -INFINITY; l_i[r] = 0.f; }
#pragma unroll
  for (int t = 0; t < 4; ++t) o[t] = (f32x4){0.f, 0.f, 0.f, 0.f};

  const float sc = 0.125f;  // 1/sqrt(64)

  for (int j = 0; j <= qt; ++j) {
#pragma unroll
    for (int i = 0; i < 2; ++i) {
      int li = wid * 2 + i;
      g2l16(k + base + (size_t)(j * 64 + li * 8 + lrow8) * HEAD_DIM + lch8, &Ks[li * 512]);
      g2l16(vt + base + (size_t)(li * 8 + lrow8) * SEQ + j * 64 + lch8, &Vs[li * 512]);
    }
    __syncthreads();  // loads complete (vmcnt drain)

    // S = Q K^T  (16x64 per wave)
    f32x4 s[4];
#pragma unroll
    for (int t = 0; t < 4; ++t) s[t] = (f32x4){0.f, 0.f, 0.f, 0.f};
    bf16x8 aq[2];
#pragma unroll
    for (int kk = 0; kk < 2; ++kk)
      aq[kk] = *(const bf16x8*)&Qs[(wid * 16 + l15) * 64 + kk * 32 + quad * 8];
#pragma unroll
    for (int t = 0; t < 4; ++t)
#pragma unroll
      for (int kk = 0; kk < 2; ++kk) {
        bf16x8 bk = *(const bf16x8*)&Ks[(t * 16 + l15) * 64 + kk * 32 + quad * 8];
        s[t] = __builtin_amdgcn_mfma_f32_16x16x32_bf16(aq[kk], bk, s[t], 0, 0, 0);
      }

    // scale + causal mask (only diagonal K-tile needs masking)
    const int row_base = qt * 64 + wid * 16 + quad * 4;
    if (j == qt) {
#pragma unroll
      for (int t = 0; t < 4; ++t) {
        int colg = j * 64 + t * 16 + l15;
#pragma unroll
        for (int r = 0; r < 4; ++r) {
          float v = s[t][r] * sc;
          s[t][r] = (colg > row_base + r) ? -INFINITY : v;
        }
      }
    } else {
#pragma unroll
      for (int t = 0; t < 4; ++t)
#pragma unroll
        for (int r = 0; r < 4; ++r) s[t][r] *= sc;
    }

    // online softmax: rowmax over 16 lanes of the quad
    float m_new[4], alpha[4], rsum[4];
#pragma unroll
    for (int r = 0; r < 4; ++r) {
      float v = fmaxf(fmaxf(s[0][r], s[1][r]), fmaxf(s[2][r], s[3][r]));
#pragma unroll
      for (int off = 1; off <= 8; off <<= 1) v = fmaxf(v, __shfl_xor(v, off));
      m_new[r] = fmaxf(m_i[r], v);
      alpha[r] = __expf(m_i[r] - m_new[r]);
      rsum[r] = 0.f;
    }

    // p = exp(s - m), stage into Ps (per-wave region)
#pragma unroll
    for (int t = 0; t < 4; ++t)
#pragma unroll
      for (int r = 0; r < 4; ++r) {
        float p = __expf(s[t][r] - m_new[r]);
        rsum[r] += p;
        Ps[wid * 1024 + (quad * 4 + r) * 64 + t * 16 + l15] = f2bf(p);
      }

#pragma unroll
    for (int r = 0; r < 4; ++r) {
      float v = rsum[r];
#pragma unroll
      for (int off = 1; off <= 8; off <<= 1) v += __shfl_xor(v, off);
      l_i[r] = l_i[r] * alpha[r] + v;
      m_i[r] = m_new[r];
    }
#pragma unroll
    for (int t = 0; t < 4; ++t)
#pragma unroll
      for (int r = 0; r < 4; ++r) o[t][r] *= alpha[r];

    __syncthreads();  // Ps visible / ordered before PV reads

    // O += P * V   (A-frag from Ps, B-frag from Vs[d][key])
    bf16x8 ap[2];
#pragma unroll
    for (int kk = 0; kk < 2; ++kk)
      ap[kk] = *(const bf16x8*)&Ps[wid * 1024 + l15 * 64 + kk * 32 + quad * 8];
#pragma unroll
    for (int t = 0; t < 4; ++t)
#pragma unroll
      for (int kk = 0; kk < 2; ++kk) {
        bf16x8 bv = *(const bf16x8*)&Vs[(t * 16 + l15) * 64 + kk * 32 + quad * 8];
        o[t] = __builtin_amdgcn_mfma_f32_16x16x32_bf16(ap[kk], bv, o[t], 0, 0, 0);
      }

    __syncthreads();  // all waves done reading Ks/Vs before next iteration's loads
  }

  const int b = bh >> 4, h = bh & 15;
#pragma unroll
  for (int r = 0; r < 4; ++r) {
    int s_row = qt * 64 + wid * 16 + quad * 4 + r;
    float inv = 1.f / l_i[r];
#pragma unroll
    for (int t = 0; t < 4; ++t)
      ctx[((size_t)(b * SEQ + s_row)) * N_EMBD + h * HEAD_DIM + t * 16 + l15] =
          f2bf(o[t][r] * inv);
  }
}

// ---------- launch ----------

extern "C" void kernel_launch(void* const* d_in, const int* in_sizes, int n_in,
                              void* d_out, int out_size, void* d_ws, size_t ws_size,
                              hipStream_t stream) {
  const float* x      = (const float*)d_in[0];
  const float* w_attn = (const float*)d_in[1];
  const float* b_attn = (const float*)d_in[2];
  const float* w_proj = (const float*)d_in[3];
  const float* b_proj = (const float*)d_in[4];
  float* out = (float*)d_out;

  char* ws = (char*)d_ws;
  u16* xb  = (u16*)(ws);                        // 8 MB (reused as ctx after GEMM1)
  u16* waT = (u16*)(ws + ((size_t)8 << 20));    // 6 MB
  u16* wpT = (u16*)(ws + ((size_t)14 << 20));   // 2 MB
  u16* qb  = (u16*)(ws + ((size_t)16 << 20));   // 8 MB
  u16* kb  = (u16*)(ws + ((size_t)24 << 20));   // 8 MB
  u16* vtb = (u16*)(ws + ((size_t)32 << 20));   // 8 MB   total 40 MB
  u16* ctx = xb;  // x (bf16) is dead after GEMM1

  conv_bf16_kernel<<<dim3((M_TOT * N_EMBD) / (256 * 8)), 256, 0, stream>>>(x, xb);
  transp_bf16_kernel<<<dim3((3 * N_EMBD) / 64, N_EMBD / 64), 256, 0, stream>>>(
      w_attn, waT, N_EMBD, 3 * N_EMBD);
  transp_bf16_kernel<<<dim3(N_EMBD / 64, N_EMBD / 64), 256, 0, stream>>>(
      w_proj, wpT, N_EMBD, N_EMBD);
  gemm_bt<1><<<dim3((3 * N_EMBD) / 128, M_TOT / 128), 256, 0, stream>>>(
      xb, waT, b_attn, nullptr, qb, kb, vtb, M_TOT, 3 * N_EMBD, N_EMBD);
  attn_kernel<<<dim3(SEQ / 64, BATCH * N_HEAD), 256, 0, stream>>>(qb, kb, vtb, ctx);
  gemm_bt<0><<<dim3(N_EMBD / 128, M_TOT / 128), 256, 0, stream>>>(
      ctx, wpT, b_proj, out, nullptr, nullptr, nullptr, M_TOT, N_EMBD, N_EMBD);
}

// Round 2
// 265.041 us; speedup vs baseline: 1.2567x; 1.2567x over previous
//
#include <hip/hip_runtime.h>
#include <hip/hip_bf16.h>
#include <cstdint>
#include <cstddef>

typedef unsigned short u16;
typedef unsigned int u32;
using bf16x8 = __attribute__((ext_vector_type(8))) __bf16;
using f32x4  = __attribute__((ext_vector_type(4))) float;

#define N_EMBD 1024
#define N_HEAD 16
#define HEAD_DIM 64
#define BATCH 2
#define SEQ 2048
#define M_TOT (BATCH * SEQ)  // 4096

// ---------- helpers ----------

__device__ __forceinline__ u16 f2bf(float f) {
  union { float f; u32 u; } v;
  v.f = f;
  u32 u = v.u;
  u32 r = (u + 0x7FFFu + ((u >> 16) & 1u)) >> 16;  // RNE
  return (u16)r;
}

__device__ __forceinline__ u32 packbf2(float a, float b) {
  union { __hip_bfloat162 h; u32 u; } cv;
  cv.h = __float22bfloat162_rn(float2{a, b});
  return cv.u;
}

// async global->LDS, 16B per lane; dst must be wave-uniform base (HW adds lane*16)
__device__ __forceinline__ void g2l16(const void* g, void* l) {
  __builtin_amdgcn_global_load_lds((__attribute__((address_space(1))) void*)(g),
                                   (__attribute__((address_space(3))) void*)(l),
                                   16, 0, 0);
}

// ---------- fp32 -> bf16 convert (x) ----------

__global__ __launch_bounds__(256) void conv_bf16_kernel(const float* __restrict__ src,
                                                        u16* __restrict__ dst) {
  int i = (blockIdx.x * 256 + threadIdx.x) * 8;
  float4 a = *(const float4*)(src + i);
  float4 b = *(const float4*)(src + i + 4);
  union { u16 s[8]; uint4 v; } o;
  o.s[0] = f2bf(a.x); o.s[1] = f2bf(a.y); o.s[2] = f2bf(a.z); o.s[3] = f2bf(a.w);
  o.s[4] = f2bf(b.x); o.s[5] = f2bf(b.y); o.s[6] = f2bf(b.z); o.s[7] = f2bf(b.w);
  *(uint4*)(dst + i) = o.v;
}

// ---------- fp32 [R][C] -> bf16 [C][R] transpose ----------

__global__ __launch_bounds__(256) void transp_bf16_kernel(const float* __restrict__ src,
                                                          u16* __restrict__ dst, int R, int C) {
  __shared__ float tile[64][65];
  const int c0 = blockIdx.x * 64, r0 = blockIdx.y * 64;
  const int tid = threadIdx.x;
#pragma unroll
  for (int i = 0; i < 16; ++i) {
    int idx = tid + i * 256;
    int r = idx >> 6, c = idx & 63;
    tile[r][c] = src[(size_t)(r0 + r) * C + (c0 + c)];
  }
  __syncthreads();
#pragma unroll
  for (int i = 0; i < 16; ++i) {
    int idx = tid + i * 256;
    int cc = idx >> 6, rr = idx & 63;
    dst[(size_t)(c0 + cc) * R + (r0 + rr)] = f2bf(tile[rr][cc]);
  }
}

// ---------- GEMM: C[M,N] = A[M,K] * Bt[N,K]^T + bias ----------
// MODE 0: fp32 out row-major [M,N]
// MODE 1: qkv epilogue -> q[B,H,S,D], k[B,H,S,D], v^T[B,H,D,S], all bf16

template <int MODE>
__global__ __launch_bounds__(256) void gemm_bt(const u16* __restrict__ A,
                                               const u16* __restrict__ Bt,
                                               const float* __restrict__ bias,
                                               float* __restrict__ outF,
                                               u16* __restrict__ qb, u16* __restrict__ kb,
                                               u16* __restrict__ vtb, int M, int N, int K) {
  __shared__ u16 As[128 * 32];
  __shared__ u16 Bs[128 * 32];
  const int tid = threadIdx.x;
  const int wid = tid >> 6;
  const int lane = tid & 63;
  const int quad = lane >> 4;
  const int l15 = lane & 15;
  const int m0 = blockIdx.y * 128;
  const int n0 = blockIdx.x * 128;
  const int wm = wid >> 1, wn = wid & 1;

  f32x4 acc[4][4];
#pragma unroll
  for (int i = 0; i < 4; ++i)
#pragma unroll
    for (int j = 0; j < 4; ++j) acc[i][j] = (f32x4){0.f, 0.f, 0.f, 0.f};

  const int lrow = lane >> 2;          // 0..15
  const int lchunk = (lane & 3) * 8;   // element offset within 32-col row

  for (int k0 = 0; k0 < K; k0 += 32) {
#pragma unroll
    for (int i = 0; i < 2; ++i) {
      int li = wid * 2 + i;
      int r = li * 16 + lrow;
      g2l16(A + (size_t)(m0 + r) * K + k0 + lchunk, &As[li * 512]);
      g2l16(Bt + (size_t)(n0 + r) * K + k0 + lchunk, &Bs[li * 512]);
    }
    __syncthreads();
    bf16x8 af[4], bfv[4];
#pragma unroll
    for (int i = 0; i < 4; ++i)
      af[i] = *(const bf16x8*)&As[(wm * 64 + i * 16 + l15) * 32 + quad * 8];
#pragma unroll
    for (int j = 0; j < 4; ++j)
      bfv[j] = *(const bf16x8*)&Bs[(wn * 64 + j * 16 + l15) * 32 + quad * 8];
#pragma unroll
    for (int i = 0; i < 4; ++i)
#pragma unroll
      for (int j = 0; j < 4; ++j)
        acc[i][j] = __builtin_amdgcn_mfma_f32_16x16x32_bf16(af[i], bfv[j], acc[i][j], 0, 0, 0);
    __syncthreads();
  }

  float bj[4];
#pragma unroll
  for (int j = 0; j < 4; ++j) bj[j] = bias[n0 + wn * 64 + j * 16 + l15];

#pragma unroll
  for (int i = 0; i < 4; ++i) {
#pragma unroll
    for (int j = 0; j < 4; ++j) {
      int col = n0 + wn * 64 + j * 16 + l15;
#pragma unroll
      for (int r = 0; r < 4; ++r) {
        int m_g = m0 + wm * 64 + i * 16 + quad * 4 + r;
        float v = acc[i][j][r] + bj[j];
        if (MODE == 0) {
          outF[(size_t)m_g * N + col] = v;
        } else {
          int which = col >> 10;      // 0=q 1=k 2=v (uniform per block: n0 is 128-aligned)
          int e = col & 1023;
          int h = e >> 6, d = e & 63;
          int b = m_g >> 11, s = m_g & 2047;
          int bh = b * N_HEAD + h;
          u16 bv = f2bf(v);
          if (which == 0)
            qb[((size_t)bh * SEQ + s) * HEAD_DIM + d] = bv;
          else if (which == 1)
            kb[((size_t)bh * SEQ + s) * HEAD_DIM + d] = bv;
          else
            vtb[((size_t)bh * HEAD_DIM + d) * SEQ + s] = bv;
        }
      }
    }
  }
}

// ---------- flash attention (causal), S^T formulation ----------
// Per block: 64 Q rows (wave w owns rows w*16..+15), K-tiles of 64, double-buffered.
// S^T = K_tile · Q^T  (MFMA A=K, B=Q) -> C-layout: lane col = q (l15), row = key.
// Softmax state per lane (one q column), replicated across quads.
// P^T staged per-wave (private, padded stride 72, no barrier) -> B-frag for
// O^T = V^T · P^T (A=V^T from [d][key] LDS). All LDS reads XOR-chunk-swizzled.

__global__ __launch_bounds__(256, 3) void attn_kernel(const u16* __restrict__ q,
                                                      const u16* __restrict__ k,
                                                      const u16* __restrict__ vt,
                                                      u16* __restrict__ ctx) {
  __shared__ u16 Qs[64 * 64];
  __shared__ u16 Ks[2][64 * 64];
  __shared__ u16 Vs[2][64 * 64];   // [d][key]
  __shared__ u16 Ps[4][16 * 72];   // per-wave P row-major [q][key], stride 72

  const int tid = threadIdx.x;
  const int wid = tid >> 6;
  const int lane = tid & 63;
  const int quad = lane >> 4;
  const int l15 = lane & 15;
  const int l7 = l15 & 7;
  const int qt = (gridDim.x - 1) - blockIdx.x;  // long blocks first
  const int bh = blockIdx.y;
  const size_t base = (size_t)bh * SEQ * HEAD_DIM;

  const int lrow8 = lane >> 3;                       // 0..7
  const int swz8 = ((lane & 7) ^ lrow8) * 8;         // swizzled source chunk (elements)

  // prologue: stage Q tile + K/V tile 0 into buf 0
#pragma unroll
  for (int i = 0; i < 2; ++i) {
    int li = wid * 2 + i;
    int r = li * 8 + lrow8;
    g2l16(q + base + (size_t)(qt * 64 + r) * HEAD_DIM + swz8, &Qs[li * 512]);
    g2l16(k + base + (size_t)r * HEAD_DIM + swz8, &Ks[0][li * 512]);
    g2l16(vt + base + (size_t)r * SEQ + swz8, &Vs[0][li * 512]);
  }

  float m_i = -INFINITY, l_i = 0.f;   // per-lane: one q column
  f32x4 o[4];
#pragma unroll
  for (int u = 0; u < 4; ++u) o[u] = (f32x4){0.f, 0.f, 0.f, 0.f};
  bf16x8 bq[2];
  const float sc = 0.125f;  // 1/sqrt(64)
  const int qrow = qt * 64 + wid * 16 + l15;

  for (int j = 0; j <= qt; ++j) {
    const int buf = j & 1;
    __syncthreads();  // drains this iter's K/V loads; frees buf^1 for prefetch

    if (j == 0) {
#pragma unroll
      for (int kk = 0; kk < 2; ++kk)
        bq[kk] = *(const bf16x8*)&Qs[(wid * 16 + l15) * 64 + (((kk * 4 + quad) ^ l7) * 8)];
    }
    if (j < qt) {
      int jn = j + 1;
#pragma unroll
      for (int i = 0; i < 2; ++i) {
        int li = wid * 2 + i;
        int r = li * 8 + lrow8;
        g2l16(k + base + (size_t)(jn * 64 + r) * HEAD_DIM + swz8, &Ks[buf ^ 1][li * 512]);
        g2l16(vt + base + (size_t)r * SEQ + jn * 64 + swz8, &Vs[buf ^ 1][li * 512]);
      }
    }

    // S^T = K · Q^T : per wave 64 keys x 16 q
    f32x4 st[4];
#pragma unroll
    for (int t = 0; t < 4; ++t) st[t] = (f32x4){0.f, 0.f, 0.f, 0.f};
#pragma unroll
    for (int kk = 0; kk < 2; ++kk) {
#pragma unroll
      for (int t = 0; t < 4; ++t) {
        bf16x8 ka = *(const bf16x8*)&Ks[buf][(t * 16 + l15) * 64 + (((kk * 4 + quad) ^ l7) * 8)];
        st[t] = __builtin_amdgcn_mfma_f32_16x16x32_bf16(ka, bq[kk], st[t], 0, 0, 0);
      }
    }

    // scale + causal mask (diagonal tile only)
    if (j == qt) {
#pragma unroll
      for (int t = 0; t < 4; ++t)
#pragma unroll
        for (int r = 0; r < 4; ++r) {
          int key = j * 64 + t * 16 + quad * 4 + r;
          float v = st[t][r] * sc;
          st[t][r] = (key > qrow) ? -INFINITY : v;
        }
    } else {
#pragma unroll
      for (int t = 0; t < 4; ++t)
#pragma unroll
        for (int r = 0; r < 4; ++r) st[t][r] *= sc;
    }

    // online softmax: per-lane over 16 values, then reduce across 4 quads
    float mx = -INFINITY;
#pragma unroll
    for (int t = 0; t < 4; ++t)
#pragma unroll
      for (int r = 0; r < 4; ++r) mx = fmaxf(mx, st[t][r]);
    mx = fmaxf(mx, __shfl_xor(mx, 16));
    mx = fmaxf(mx, __shfl_xor(mx, 32));
    float m_new = fmaxf(m_i, mx);
    float alpha = __expf(m_i - m_new);
    float rs = 0.f;
#pragma unroll
    for (int t = 0; t < 4; ++t)
#pragma unroll
      for (int r = 0; r < 4; ++r) {
        float p = __expf(st[t][r] - m_new);
        st[t][r] = p;
        rs += p;
      }
    rs += __shfl_xor(rs, 16);
    rs += __shfl_xor(rs, 32);
    l_i = l_i * alpha + rs;
    m_i = m_new;
#pragma unroll
    for (int u = 0; u < 4; ++u)
#pragma unroll
      for (int r = 0; r < 4; ++r) o[u][r] *= alpha;

    // stage P row-major [q][key] (per-wave private; packed b64; no barrier)
#pragma unroll
    for (int t = 0; t < 4; ++t) {
      uint2 pk;
      pk.x = packbf2(st[t][0], st[t][1]);
      pk.y = packbf2(st[t][2], st[t][3]);
      *(uint2*)&Ps[wid][l15 * 72 + t * 16 + quad * 4] = pk;
    }

    // O^T += V^T · P^T
#pragma unroll
    for (int kk = 0; kk < 2; ++kk) {
      bf16x8 bp = *(const bf16x8*)&Ps[wid][l15 * 72 + kk * 32 + quad * 8];
#pragma unroll
      for (int u = 0; u < 4; ++u) {
        bf16x8 va = *(const bf16x8*)&Vs[buf][(u * 16 + l15) * 64 + (((kk * 4 + quad) ^ l7) * 8)];
        o[u] = __builtin_amdgcn_mfma_f32_16x16x32_bf16(va, bp, o[u], 0, 0, 0);
      }
    }
  }

  // epilogue: O^T C-layout -> ctx[b][s=q][h*64+d]; lane has q=l15, d=u*16+quad*4+r
  const int b = bh >> 4, h = bh & 15;
  const float inv = 1.f / l_i;
  const size_t rowbase = ((size_t)(b * SEQ + qrow)) * N_EMBD + h * HEAD_DIM;
#pragma unroll
  for (int u = 0; u < 4; ++u) {
    uint2 pk;
    pk.x = packbf2(o[u][0] * inv, o[u][1] * inv);
    pk.y = packbf2(o[u][2] * inv, o[u][3] * inv);
    *(uint2*)&ctx[rowbase + u * 16 + quad * 4] = pk;
  }
}

// ---------- launch ----------

extern "C" void kernel_launch(void* const* d_in, const int* in_sizes, int n_in,
                              void* d_out, int out_size, void* d_ws, size_t ws_size,
                              hipStream_t stream) {
  const float* x      = (const float*)d_in[0];
  const float* w_attn = (const float*)d_in[1];
  const float* b_attn = (const float*)d_in[2];
  const float* w_proj = (const float*)d_in[3];
  const float* b_proj = (const float*)d_in[4];
  float* out = (float*)d_out;

  char* ws = (char*)d_ws;
  u16* xb  = (u16*)(ws);                        // 8 MB (reused as ctx after GEMM1)
  u16* waT = (u16*)(ws + ((size_t)8 << 20));    // 6 MB
  u16* wpT = (u16*)(ws + ((size_t)14 << 20));   // 2 MB
  u16* qb  = (u16*)(ws + ((size_t)16 << 20));   // 8 MB
  u16* kb  = (u16*)(ws + ((size_t)24 << 20));   // 8 MB
  u16* vtb = (u16*)(ws + ((size_t)32 << 20));   // 8 MB   total 40 MB
  u16* ctx = xb;  // x (bf16) is dead after GEMM1

  conv_bf16_kernel<<<dim3((M_TOT * N_EMBD) / (256 * 8)), 256, 0, stream>>>(x, xb);
  transp_bf16_kernel<<<dim3((3 * N_EMBD) / 64, N_EMBD / 64), 256, 0, stream>>>(
      w_attn, waT, N_EMBD, 3 * N_EMBD);
  transp_bf16_kernel<<<dim3(N_EMBD / 64, N_EMBD / 64), 256, 0, stream>>>(
      w_proj, wpT, N_EMBD, N_EMBD);
  gemm_bt<1><<<dim3((3 * N_EMBD) / 128, M_TOT / 128), 256, 0, stream>>>(
      xb, waT, b_attn, nullptr, qb, kb, vtb, M_TOT, 3 * N_EMBD, N_EMBD);
  attn_kernel<<<dim3(SEQ / 64, BATCH * N_HEAD), 256, 0, stream>>>(qb, kb, vtb, ctx);
  gemm_bt<0><<<dim3(N_EMBD / 128, M_TOT / 128), 256, 0, stream>>>(
      ctx, wpT, b_proj, out, nullptr, nullptr, nullptr, M_TOT, N_EMBD, N_EMBD);
}